// Round 1
// baseline (1300.002 us; speedup 1.0000x reference)
//
#include <hip/hip_runtime.h>
#include <math.h>

#define NROWS 8192
#define NC    32000
#define NV4   (NC / 4)   // 8000 float4 per row
#define BLK   256

// One block per row: single-pass online logsumexp over 32000 fp32 logits,
// then focal-loss term for the target class, atomicAdd into scalar out.
__global__ __launch_bounds__(BLK) void focal_loss_kernel(
    const float* __restrict__ x,
    const int*   __restrict__ target,
    float*       __restrict__ out)
{
    const int row  = blockIdx.x;
    const int tid  = threadIdx.x;
    const float4* xr = (const float4*)(x + (size_t)row * NC);

    // Online logsumexp state (per thread)
    float m = -INFINITY;
    float s = 0.0f;

    for (int i = tid; i < NV4; i += BLK) {
        float4 v = xr[i];
        float m4 = fmaxf(fmaxf(v.x, v.y), fmaxf(v.z, v.w));
        float nm = fmaxf(m, m4);
        // rescale old sum once, add 4 independent exps (good ILP)
        s = s * __expf(m - nm)
          + __expf(v.x - nm) + __expf(v.y - nm)
          + __expf(v.z - nm) + __expf(v.w - nm);
        m = nm;
    }

    // Wave (64-lane) butterfly-style reduction via shfl_down
    #pragma unroll
    for (int off = 32; off > 0; off >>= 1) {
        float m2 = __shfl_down(m, off, 64);
        float s2 = __shfl_down(s, off, 64);
        float nm = fmaxf(m, m2);
        s = s * __expf(m - nm) + s2 * __expf(m2 - nm);
        m = nm;
    }

    // Cross-wave reduction through LDS (4 waves per block)
    __shared__ float sm[BLK / 64];
    __shared__ float ss[BLK / 64];
    const int wave = tid >> 6;
    const int lane = tid & 63;
    if (lane == 0) { sm[wave] = m; ss[wave] = s; }
    __syncthreads();

    if (tid == 0) {
        float M = sm[0], S = ss[0];
        #pragma unroll
        for (int w = 1; w < BLK / 64; ++w) {
            float nm = fmaxf(M, sm[w]);
            S = S * __expf(M - nm) + ss[w] * __expf(sm[w] - nm);
            M = nm;
        }
        const float lse = M + logf(S);

        const int t   = target[row];
        const float xt = x[(size_t)row * NC + t];
        const float logpt = xt - lse;
        const float pt = expf(logpt);

        // FLSD-53 bucket: gamma = 5 if pt < 0.2 else 3 (pt>=0.5 and mid both 3)
        const float u  = 1.0f - pt;
        const float u3 = u * u * u;
        const float w  = (pt < 0.2f) ? (u3 * u * u) : u3;

        atomicAdd(out, -w * logpt);
    }
}

extern "C" void kernel_launch(void* const* d_in, const int* in_sizes, int n_in,
                              void* d_out, int out_size, void* d_ws, size_t ws_size,
                              hipStream_t stream) {
    const float* x      = (const float*)d_in[0];
    const int*   target = (const int*)d_in[1];
    float*       out    = (float*)d_out;

    // d_out is re-poisoned to 0xAA before every timed launch — zero it here.
    hipMemsetAsync(out, 0, sizeof(float), stream);

    focal_loss_kernel<<<NROWS, BLK, 0, stream>>>(x, target, out);
}